// Round 6
// baseline (3537.162 us; speedup 1.0000x reference)
//
#include <hip/hip_runtime.h>
#include <cstdint>

typedef unsigned short u16;
typedef short bf16x8 __attribute__((ext_vector_type(8)));
typedef float f32x4 __attribute__((ext_vector_type(4)));

typedef const __attribute__((address_space(1))) unsigned int* gas1_t;
typedef __attribute__((address_space(3))) unsigned int* las3_t;

__device__ __forceinline__ float bf2f(u16 u) {
    union { unsigned u; float f; } v; v.u = ((unsigned)u) << 16; return v.f;
}
__device__ __forceinline__ u16 f2bf(float f) {
    union { float f; unsigned u; } v; v.f = f;
    return (u16)((v.u + 0x7FFFu + ((v.u >> 16) & 1u)) >> 16);
}
// global->LDS direct DMA, 16B per lane. LDS dest is wave-uniform base + lane*16.
__device__ __forceinline__ void gload_lds16(const void* g, void* l) {
    gas1_t gp = reinterpret_cast<gas1_t>(reinterpret_cast<uintptr_t>(g));
    las3_t lp = reinterpret_cast<las3_t>(static_cast<uint32_t>(reinterpret_cast<uintptr_t>(l)));
    __builtin_amdgcn_global_load_lds(gp, lp, 16, 0, 0);
}
__device__ __forceinline__ float sigf(float x) { return 1.0f / (1.0f + __expf(-x)); }
__device__ __forceinline__ float tanhf_(float x) { return 2.0f / (1.0f + __expf(-2.0f * x)) - 1.0f; }

// --- cross-XCD coherent ops (device coherence point, sc0 sc1) ---
__device__ __forceinline__ void storeh1_cc(u16* p, unsigned v) {
    asm volatile("global_store_dword %0, %1, off sc0 sc1" :: "v"(p), "v"(v) : "memory");
}
__device__ __forceinline__ uint4 loadh_cc(const u16* p) {
    uint4 r;
    asm volatile("global_load_dwordx4 %0, %1, off sc0 sc1" : "=v"(r) : "v"(p) : "memory");
    return r;
}
__device__ __forceinline__ void waitcnt0() {
    asm volatile("s_waitcnt vmcnt(0)" ::: "memory");
}
// canary = bf16 0xFFFF (NaN). |h| <= 1 and f2bf of a finite float in [-1,1]
// never produces 0xFFFF, so canary != any real h (R4 verified end-to-end).
__device__ __forceinline__ bool dw_can(unsigned d) {
    return ((d & 0xFFFFu) == 0xFFFFu) || ((d >> 16) == 0xFFFFu);
}
__device__ __forceinline__ bool any_can(uint4 v) {
    return dw_can(v.x) || dw_can(v.y) || dw_can(v.z) || dw_can(v.w);
}

// ---------------------------------------------------------------------------
// K0: prep — gather embeddings -> xsb (bf16), convert W_ih_f|W_ih_b -> wcat,
//            W_lin (padded to 32 rows) -> wlp
// ---------------------------------------------------------------------------
__global__ __launch_bounds__(256) void k_prep(const int* __restrict__ x, const float* __restrict__ emb,
        const float* __restrict__ wihf, const float* __restrict__ wihb, const float* __restrict__ wlin,
        u16* __restrict__ xsb, u16* __restrict__ wcat, u16* __restrict__ wlp) {
    int gid = blockIdx.x * 256 + threadIdx.x;
    const float* src = nullptr;
    u16* dst = nullptr;
    bool zero = false;
    if (gid < 2097152) {
        int row = gid >> 6, k0 = (gid & 63) << 3;
        int t = row >> 6, b = row & 63;
        int tok = x[b * 512 + t];
        src = emb + (size_t)tok * 512 + k0;
        dst = xsb + (size_t)row * 512 + k0;
    } else if (gid < 2359296) {
        int wid = gid - 2097152;
        int n = wid >> 6, k0 = (wid & 63) << 3;
        src = (n < 2048) ? (wihf + (size_t)n * 512 + k0) : (wihb + (size_t)(n - 2048) * 512 + k0);
        dst = wcat + (size_t)n * 512 + k0;
    } else {
        int wid = gid - 2359296;
        int n = wid >> 7, k0 = (wid & 127) << 3;
        dst = wlp + (size_t)n * 1024 + k0;
        if (n < 21) src = wlin + (size_t)n * 1024 + k0; else zero = true;
    }
    uint4 ov;
    if (zero) {
        ov.x = ov.y = ov.z = ov.w = 0u;
    } else {
        float4 a = *(const float4*)src;
        float4 b4 = *(const float4*)(src + 4);
        ov.x = (unsigned)f2bf(a.x) | ((unsigned)f2bf(a.y) << 16);
        ov.y = (unsigned)f2bf(a.z) | ((unsigned)f2bf(a.w) << 16);
        ov.z = (unsigned)f2bf(b4.x) | ((unsigned)f2bf(b4.y) << 16);
        ov.w = (unsigned)f2bf(b4.z) | ((unsigned)f2bf(b4.w) << 16);
    }
    *(uint4*)dst = ov;
}

// ---------------------------------------------------------------------------
// K1: xg[m][4096] = xsb @ wcat^T + bias (bf16 out). 128x128 tile, BK=32.
// ---------------------------------------------------------------------------
__global__ __launch_bounds__(256) void k_gemm_xg(const u16* __restrict__ xsb, const u16* __restrict__ wcat,
        const float* __restrict__ bihf, const float* __restrict__ bhhf,
        const float* __restrict__ bihb, const float* __restrict__ bhhb,
        u16* __restrict__ xg) {
    __shared__ __align__(16) u16 Al[4096];
    __shared__ __align__(16) u16 Bl[4096];
    int tid = threadIdx.x;
    int lane = tid & 63, w = tid >> 6;
    int l16 = lane & 15, q = lane >> 4;
    int m0 = blockIdx.x * 128, n0 = blockIdx.y * 128;
    int mtb = (w & 1) * 4, ntb = (w >> 1) * 4;
    f32x4 acc[4][4];
    for (int a = 0; a < 4; ++a)
        for (int bb = 0; bb < 4; ++bb)
            for (int r = 0; r < 4; ++r) acc[a][bb][r] = 0.f;
    for (int kk = 0; kk < 16; ++kk) {
        int kb = kk * 32;
        __syncthreads();
        for (int i = 0; i < 2; ++i) {
            int wbase = i * 256 + w * 64;
            int slot = wbase + lane;
            int aq = slot >> 7, am = slot & 127;
            gload_lds16(xsb + (size_t)(m0 + am) * 512 + kb + aq * 8, Al + wbase * 8);
            gload_lds16(wcat + (size_t)(n0 + am) * 512 + kb + aq * 8, Bl + wbase * 8);
        }
        __syncthreads();
        bf16x8 af[4], bfr[4];
#pragma unroll
        for (int mt = 0; mt < 4; ++mt) af[mt] = *(const bf16x8*)(Al + (q * 128 + (mtb + mt) * 16 + l16) * 8);
#pragma unroll
        for (int nt = 0; nt < 4; ++nt) bfr[nt] = *(const bf16x8*)(Bl + (q * 128 + (ntb + nt) * 16 + l16) * 8);
#pragma unroll
        for (int mt = 0; mt < 4; ++mt)
#pragma unroll
            for (int nt = 0; nt < 4; ++nt)
                acc[mt][nt] = __builtin_amdgcn_mfma_f32_16x16x32_bf16(af[mt], bfr[nt], acc[mt][nt], 0, 0, 0);
    }
    float bias[4];
    for (int nt = 0; nt < 4; ++nt) {
        int gn = n0 + (ntb + nt) * 16 + l16;
        int rr = gn & 2047;
        bias[nt] = (gn >> 11) ? (bihb[rr] + bhhb[rr]) : (bihf[rr] + bhhf[rr]);
    }
    for (int mt = 0; mt < 4; ++mt)
        for (int nt = 0; nt < 4; ++nt)
            for (int r = 0; r < 4; ++r) {
                int gm = m0 + (mtb + mt) * 16 + q * 4 + r;
                int gn = n0 + (ntb + nt) * 16 + l16;
                xg[(size_t)gm * 4096 + gn] = f2bf(acc[mt][nt][r] + bias[nt]);
            }
}

// ---------------------------------------------------------------------------
// K2: persistent bidirectional LSTM. 64 blocks x 512 threads (32 per dir),
// R5's gate-split structure. Sync = batched data-validity polling:
//  - h buffers pre-filled with bf16 0xFFFF canary; producers fire-and-forget
//    store (no ack, no barrier C, no flag, no atomic).
//  - consumers issue all 8 coalesced row loads, one waitcnt, then re-issue
//    ONLY stale chunks together per round (1 RT/round, vs R4's serial 8 RT).
//  - barrier B protects hlds reuse across steps; barrier A joins waves.
// ---------------------------------------------------------------------------
__global__ __launch_bounds__(512) void k_lstm(const u16* __restrict__ xg,
        const float* __restrict__ whhf, const float* __restrict__ whhb,
        u16* __restrict__ hf, u16* __restrict__ hb) {
    __shared__ __align__(16) u16 hlds[32768];   // 64 KB
    __shared__ float gbuf[64 * 65];             // 16.6 KB
    int tid = threadIdx.x;
    int lane = tid & 63, w = tid >> 6;
    int l16 = lane & 15, q = lane >> 4;
    int dir = blockIdx.x >> 5, blk = blockIdx.x & 31;
    int j0 = blk * 16;
    const float* whh = dir ? whhb : whhf;
    u16* hbuf = dir ? hb : hf;
    // register-resident W_hh fragments: wave (w&3) owns local gate rows
    // 16*(w&3)..+15 (waves 4-7 duplicate, handling batch rows 32-63)
    int nloc = 16 * (w & 3) + l16;       // 0..63
    int gate = nloc >> 4, jl = nloc & 15;
    int grow = gate * 512 + j0 + jl;
    int mtb = (w >> 2) * 2;              // batch tile base: 0 or 2
    bf16x8 wf[16];
    for (int kc = 0; kc < 16; ++kc) {
        const float* sp = whh + (size_t)grow * 512 + kc * 32 + q * 8;
        float4 a = *(const float4*)sp;
        float4 b4 = *(const float4*)(sp + 4);
        bf16x8 tv;
        tv[0] = (short)f2bf(a.x);  tv[1] = (short)f2bf(a.y);
        tv[2] = (short)f2bf(a.z);  tv[3] = (short)f2bf(a.w);
        tv[4] = (short)f2bf(b4.x); tv[5] = (short)f2bf(b4.y);
        tv[6] = (short)f2bf(b4.z); tv[7] = (short)f2bf(b4.w);
        wf[kc] = tv;
    }
    int b = tid >> 3, jc = (tid & 7) << 1;  // update-phase: 2 cols per thread
    float cst[2] = {0.f, 0.f};
    // preload xg for step 0 (4 gates x 2 cols)
    ushort2 xv0, xv1, xv2, xv3;
    {
        int t = dir ? 511 : 0;
        const u16* xgr = xg + ((size_t)(t * 64 + b)) * 4096 + dir * 2048 + j0 + jc;
        xv0 = *(const ushort2*)(xgr);
        xv1 = *(const ushort2*)(xgr + 512);
        xv2 = *(const ushort2*)(xgr + 1024);
        xv3 = *(const ushort2*)(xgr + 1536);
    }
    for (int s = 0; s < 512; ++s) {
        int t = dir ? (511 - s) : s;
        f32x4 acc[2];
        if (s > 0) {
            // --- stage full h_prev -> LDS: coalesced rows + batched canary ---
            int tp = dir ? (t + 1) : (t - 1);
            const u16* hsrc = hbuf + (size_t)tp * 32768;
            const u16* srcs[8];
            uint4 rv[8];
#pragma unroll
            for (int it = 0; it < 8; ++it) {
                int cr = it * 8 + w;  // batch row
                srcs[it] = hsrc + (size_t)cr * 512 + lane * 8;
                rv[it] = loadh_cc(srcs[it]);
            }
            waitcnt0();
            for (;;) {
                bool stale = false;
#pragma unroll
                for (int it = 0; it < 8; ++it) stale = stale || any_can(rv[it]);
                if (__ballot(stale) == 0ull) break;
                __builtin_amdgcn_s_sleep(1);
#pragma unroll
                for (int it = 0; it < 8; ++it)
                    if (any_can(rv[it])) rv[it] = loadh_cc(srcs[it]);
                waitcnt0();
            }
#pragma unroll
            for (int it = 0; it < 8; ++it) {
                int cr = it * 8 + w;
                int ps = lane * 64 + (cr ^ lane);  // kcq = lane
                *(uint4*)(hlds + (size_t)ps * 8) = rv[it];
            }
            __syncthreads();  // (A) staging visible
#pragma unroll
            for (int mi = 0; mi < 2; ++mi)
                for (int r = 0; r < 4; ++r) acc[mi][r] = 0.f;
#pragma unroll
            for (int kc = 0; kc < 16; ++kc) {
                int kcq = kc * 4 + q;
#pragma unroll
                for (int mi = 0; mi < 2; ++mi) {
                    int m = (mtb + mi) * 16 + l16;
                    bf16x8 a = *(const bf16x8*)(hlds + (size_t)(kcq * 64 + (m ^ kcq)) * 8);
                    acc[mi] = __builtin_amdgcn_mfma_f32_16x16x32_bf16(a, wf[kc], acc[mi], 0, 0, 0);
                }
            }
            for (int mi = 0; mi < 2; ++mi)
                for (int r = 0; r < 4; ++r)
                    gbuf[nloc * 65 + (mtb + mi) * 16 + q * 4 + r] = acc[mi][r];
            __syncthreads();  // (B) gates visible; hlds free after this
        }
        // --- elementwise gate update (2 cells per thread) ---
        float hv[2];
        const u16* x0 = (const u16*)&xv0;
        const u16* x1 = (const u16*)&xv1;
        const u16* x2 = (const u16*)&xv2;
        const u16* x3 = (const u16*)&xv3;
#pragma unroll
        for (int p = 0; p < 2; ++p) {
            int jj = jc + p;
            float gi = bf2f(x0[p]);
            float gf = bf2f(x1[p]);
            float gg = bf2f(x2[p]);
            float go = bf2f(x3[p]);
            if (s > 0) {
                gi += gbuf[jj * 65 + b];
                gf += gbuf[(16 + jj) * 65 + b];
                gg += gbuf[(32 + jj) * 65 + b];
                go += gbuf[(48 + jj) * 65 + b];
            }
            float cc = sigf(gf) * cst[p] + sigf(gi) * tanhf_(gg);
            cst[p] = cc;
            hv[p] = sigf(go) * tanhf_(cc);
        }
        unsigned pk = (unsigned)f2bf(hv[0]) | ((unsigned)f2bf(hv[1]) << 16);
        storeh1_cc(hbuf + ((size_t)(t * 64 + b)) * 512 + j0 + jc, pk);
        // fire-and-forget: consumers detect via data canary
        if (s < 511) {
            // prefetch next step's xg (normal cached loads; consumed after
            // next staging, so they stay in flight under the poll)
            int tn = dir ? (t - 1) : (t + 1);
            const u16* xgr = xg + ((size_t)(tn * 64 + b)) * 4096 + dir * 2048 + j0 + jc;
            xv0 = *(const ushort2*)(xgr);
            xv1 = *(const ushort2*)(xgr + 512);
            xv2 = *(const ushort2*)(xgr + 1024);
            xv3 = *(const ushort2*)(xgr + 1536);
        } else {
            waitcnt0();  // drain final h stores before endpgm
        }
    }
}

// ---------------------------------------------------------------------------
// K3: em[m][21] = [hf[m], hb[m]] @ wlp^T + b_lin   (f32 out)
// ---------------------------------------------------------------------------
__global__ __launch_bounds__(256) void k_em(const u16* __restrict__ hf, const u16* __restrict__ hb,
        const u16* __restrict__ wlp, const float* __restrict__ blin, float* __restrict__ em) {
    __shared__ __align__(16) u16 Al[4096];
    __shared__ __align__(16) u16 Bl[1024];
    int tid = threadIdx.x;
    int lane = tid & 63, w = tid >> 6;
    int l16 = lane & 15, q = lane >> 4;
    int m0 = blockIdx.x * 128;
    f32x4 acc[2][2];
    for (int a = 0; a < 2; ++a)
        for (int bb = 0; bb < 2; ++bb)
            for (int r = 0; r < 4; ++r) acc[a][bb][r] = 0.f;
    for (int kc = 0; kc < 32; ++kc) {
        __syncthreads();
        for (int i = 0; i < 2; ++i) {
            int wbase = i * 256 + w * 64;
            int slot = wbase + lane;
            int aq = slot >> 7, am = slot & 127;
            int k = kc * 32 + aq * 8;
            const u16* src = (k < 512) ? (hf + (size_t)(m0 + am) * 512 + k)
                                       : (hb + (size_t)(m0 + am) * 512 + (k - 512));
            gload_lds16(src, Al + wbase * 8);
        }
        if (w < 2) {
            int slot = tid;
            int bq = slot >> 5, bn = slot & 31;
            gload_lds16(wlp + (size_t)bn * 1024 + kc * 32 + bq * 8, Bl + w * 64 * 8);
        }
        __syncthreads();
        bf16x8 af[2], bfr[2];
#pragma unroll
        for (int mi = 0; mi < 2; ++mi) af[mi] = *(const bf16x8*)(Al + (q * 128 + (w * 2 + mi) * 16 + l16) * 8);
#pragma unroll
        for (int ni = 0; ni < 2; ++ni) bfr[ni] = *(const bf16x8*)(Bl + (q * 32 + ni * 16 + l16) * 8);
#pragma unroll
        for (int mi = 0; mi < 2; ++mi)
#pragma unroll
            for (int ni = 0; ni < 2; ++ni)
                acc[mi][ni] = __builtin_amdgcn_mfma_f32_16x16x32_bf16(af[mi], bfr[ni], acc[mi][ni], 0, 0, 0);
    }
    for (int mi = 0; mi < 2; ++mi)
        for (int ni = 0; ni < 2; ++ni)
            for (int r = 0; r < 4; ++r) {
                int gm = m0 + (w * 2 + mi) * 16 + q * 4 + r;
                int tag = ni * 16 + l16;
                if (tag < 21) em[(size_t)gm * 21 + tag] = acc[mi][ni][r] + blin[tag];
            }
}

// ---------------------------------------------------------------------------
// K4: CRF forward + numerator. One wave per batch element.
// ---------------------------------------------------------------------------
__global__ __launch_bounds__(64) void k_crf(const float* __restrict__ em, const int* __restrict__ y,
        const int* __restrict__ sl, const float* __restrict__ st, const float* __restrict__ en,
        const float* __restrict__ tr, float* __restrict__ out) {
    int b = blockIdx.x;
    int j = threadIdx.x;
    bool act = j < 21;
    int seqlen = sl[b];
    float E[21];
    for (int i = 0; i < 21; ++i) E[i] = act ? __expf(tr[i * 21 + j]) : 1.0f;
    float alpha = act ? (st[j] + em[(size_t)b * 21 + j]) : -1e30f;
    float endv = act ? en[j] : 0.0f;
    float num = 0.0f;
    int tagp = 0;
    if (j == 0) {
        int t0 = y[b * 512];
        num = st[t0] + em[(size_t)b * 21 + t0];
        tagp = t0;
    }
    for (int t = 1; t < 512; ++t) {
        bool m = t < seqlen;
        float emv = act ? em[((size_t)t * 64 + b) * 21 + j] : 0.0f;
        float mx = alpha;
        for (int o = 16; o > 0; o >>= 1) mx = fmaxf(mx, __shfl_xor(mx, o, 32));
        float e = __expf(alpha - mx);
        float s = 0.0f;
#pragma unroll
        for (int i = 0; i < 21; ++i) s += __shfl(e, i) * E[i];
        float nxt = mx + __logf(s) + emv;
        if (m && act) alpha = nxt;
        if (m && j == 0) {
            int tc = y[b * 512 + t];
            num += tr[tagp * 21 + tc] + em[((size_t)t * 64 + b) * 21 + tc];
            tagp = tc;
        }
    }
    if (j == 0) num += en[y[b * 512 + seqlen - 1]];
    float v = act ? (alpha + endv) : -1e30f;
    float mz = v;
    for (int o = 16; o > 0; o >>= 1) mz = fmaxf(mz, __shfl_xor(mz, o, 32));
    float ez = act ? __expf(v - mz) : 0.0f;
    for (int o = 16; o > 0; o >>= 1) ez += __shfl_xor(ez, o, 32);
    float logZ = mz + __logf(ez);
    if (j == 0) atomicAdd(out, logZ - num);
}

__global__ void k_sentinel(float* out) {
    if (threadIdx.x == 0 && blockIdx.x == 0) out[0] = 123456.0f;
}

// ---------------------------------------------------------------------------
extern "C" void kernel_launch(void* const* d_in, const int* in_sizes, int n_in,
                              void* d_out, int out_size, void* d_ws, size_t ws_size,
                              hipStream_t stream) {
    const int*   x    = (const int*)d_in[0];
    const int*   y    = (const int*)d_in[1];
    const int*   sl   = (const int*)d_in[2];
    const float* emb  = (const float*)d_in[3];
    const float* wihf = (const float*)d_in[4];
    const float* whhf = (const float*)d_in[5];
    const float* bihf = (const float*)d_in[6];
    const float* bhhf = (const float*)d_in[7];
    const float* wihb = (const float*)d_in[8];
    const float* whhb = (const float*)d_in[9];
    const float* bihb = (const float*)d_in[10];
    const float* bhhb = (const float*)d_in[11];
    const float* wlin = (const float*)d_in[12];
    const float* blin = (const float*)d_in[13];
    const float* st   = (const float*)d_in[14];
    const float* en   = (const float*)d_in[15];
    const float* tr   = (const float*)d_in[16];

    const size_t OFF_XG   = 0;
    const size_t OFF_XSB  = 268435456;
    const size_t OFF_WCAT = 301989888;
    const size_t OFF_HF   = 306184192;
    const size_t OFF_HB   = 339738624;
    const size_t OFF_EM   = 373293056;
    const size_t OFF_WLP  = 376045568;
    const size_t OFF_CNT  = 376111104;
    const size_t NEEDED   = OFF_CNT + 4096;

    if (ws_size < NEEDED) {
        k_sentinel<<<1, 64, 0, stream>>>((float*)d_out);
        return;
    }
    char* ws = (char*)d_ws;
    u16*      xg   = (u16*)(ws + OFF_XG);
    u16*      xsb  = (u16*)(ws + OFF_XSB);
    u16*      wcat = (u16*)(ws + OFF_WCAT);
    u16*      hf   = (u16*)(ws + OFF_HF);
    u16*      hb   = (u16*)(ws + OFF_HB);
    float*    em   = (float*)(ws + OFF_EM);
    u16*      wlp  = (u16*)(ws + OFF_WLP);

    // canary-fill h buffers (bf16 0xFFFF = impossible h value)
    hipMemsetAsync(hf, 0xFF, 33554432, stream);
    hipMemsetAsync(hb, 0xFF, 33554432, stream);
    hipMemsetAsync(d_out, 0, sizeof(float), stream);

    k_prep<<<9232, 256, 0, stream>>>(x, emb, wihf, wihb, wlin, xsb, wcat, wlp);
    k_gemm_xg<<<dim3(256, 32), 256, 0, stream>>>(xsb, wcat, bihf, bhhf, bihb, bhhb, xg);
    k_lstm<<<64, 512, 0, stream>>>(xg, whhf, whhb, hf, hb);
    k_em<<<256, 256, 0, stream>>>(hf, hb, wlp, blin, em);
    k_crf<<<64, 64, 0, stream>>>(em, y, sl, st, en, tr, (float*)d_out);
}

// Round 7
// 2759.069 us; speedup vs baseline: 1.2820x; 1.2820x over previous
//
#include <hip/hip_runtime.h>
#include <cstdint>

typedef unsigned short u16;
typedef short bf16x8 __attribute__((ext_vector_type(8)));
typedef float f32x4 __attribute__((ext_vector_type(4)));

typedef const __attribute__((address_space(1))) unsigned int* gas1_t;
typedef __attribute__((address_space(3))) unsigned int* las3_t;

__device__ __forceinline__ float bf2f(u16 u) {
    union { unsigned u; float f; } v; v.u = ((unsigned)u) << 16; return v.f;
}
__device__ __forceinline__ u16 f2bf(float f) {
    union { float f; unsigned u; } v; v.f = f;
    return (u16)((v.u + 0x7FFFu + ((v.u >> 16) & 1u)) >> 16);
}
// global->LDS direct DMA, 16B per lane. LDS dest is wave-uniform base + lane*16.
__device__ __forceinline__ void gload_lds16(const void* g, void* l) {
    gas1_t gp = reinterpret_cast<gas1_t>(reinterpret_cast<uintptr_t>(g));
    las3_t lp = reinterpret_cast<las3_t>(static_cast<uint32_t>(reinterpret_cast<uintptr_t>(l)));
    __builtin_amdgcn_global_load_lds(gp, lp, 16, 0, 0);
}
__device__ __forceinline__ float sigf(float x) { return 1.0f / (1.0f + __expf(-x)); }
__device__ __forceinline__ float tanhf_(float x) { return 2.0f / (1.0f + __expf(-2.0f * x)) - 1.0f; }

// --- cross-XCD coherent ops (device coherence point, sc0 sc1) ---
__device__ __forceinline__ void storeh1_cc(u16* p, unsigned v) {
    asm volatile("global_store_dword %0, %1, off sc0 sc1" :: "v"(p), "v"(v) : "memory");
}
__device__ __forceinline__ uint4 loadh_cc(const u16* p) {
    uint4 r;
    asm volatile("global_load_dwordx4 %0, %1, off sc0 sc1" : "=v"(r) : "v"(p) : "memory");
    return r;
}
__device__ __forceinline__ unsigned loadflag_cc(const unsigned* p) {
    unsigned r;
    asm volatile("global_load_dword %0, %1, off sc0 sc1\n\ts_waitcnt vmcnt(0)"
                 : "=v"(r) : "v"(p) : "memory");
    return r;
}
__device__ __forceinline__ void storeflag_cc(unsigned* p, unsigned v) {
    asm volatile("global_store_dword %0, %1, off sc0 sc1" :: "v"(p), "v"(v) : "memory");
}
__device__ __forceinline__ void waitcnt0() {
    asm volatile("s_waitcnt vmcnt(0)" ::: "memory");
}

// ---------------------------------------------------------------------------
// K0: prep — gather embeddings -> xsb (bf16), convert W_ih_f|W_ih_b -> wcat,
//            W_lin (padded to 32 rows) -> wlp
// ---------------------------------------------------------------------------
__global__ __launch_bounds__(256) void k_prep(const int* __restrict__ x, const float* __restrict__ emb,
        const float* __restrict__ wihf, const float* __restrict__ wihb, const float* __restrict__ wlin,
        u16* __restrict__ xsb, u16* __restrict__ wcat, u16* __restrict__ wlp) {
    int gid = blockIdx.x * 256 + threadIdx.x;
    const float* src = nullptr;
    u16* dst = nullptr;
    bool zero = false;
    if (gid < 2097152) {
        int row = gid >> 6, k0 = (gid & 63) << 3;
        int t = row >> 6, b = row & 63;
        int tok = x[b * 512 + t];
        src = emb + (size_t)tok * 512 + k0;
        dst = xsb + (size_t)row * 512 + k0;
    } else if (gid < 2359296) {
        int wid = gid - 2097152;
        int n = wid >> 6, k0 = (wid & 63) << 3;
        src = (n < 2048) ? (wihf + (size_t)n * 512 + k0) : (wihb + (size_t)(n - 2048) * 512 + k0);
        dst = wcat + (size_t)n * 512 + k0;
    } else {
        int wid = gid - 2359296;
        int n = wid >> 7, k0 = (wid & 127) << 3;
        dst = wlp + (size_t)n * 1024 + k0;
        if (n < 21) src = wlin + (size_t)n * 1024 + k0; else zero = true;
    }
    uint4 ov;
    if (zero) {
        ov.x = ov.y = ov.z = ov.w = 0u;
    } else {
        float4 a = *(const float4*)src;
        float4 b4 = *(const float4*)(src + 4);
        ov.x = (unsigned)f2bf(a.x) | ((unsigned)f2bf(a.y) << 16);
        ov.y = (unsigned)f2bf(a.z) | ((unsigned)f2bf(a.w) << 16);
        ov.z = (unsigned)f2bf(b4.x) | ((unsigned)f2bf(b4.y) << 16);
        ov.w = (unsigned)f2bf(b4.z) | ((unsigned)f2bf(b4.w) << 16);
    }
    *(uint4*)dst = ov;
}

// ---------------------------------------------------------------------------
// K1: xg[m][4096] = xsb @ wcat^T + bias (bf16 out). 128x128 tile, BK=32.
// ---------------------------------------------------------------------------
__global__ __launch_bounds__(256) void k_gemm_xg(const u16* __restrict__ xsb, const u16* __restrict__ wcat,
        const float* __restrict__ bihf, const float* __restrict__ bhhf,
        const float* __restrict__ bihb, const float* __restrict__ bhhb,
        u16* __restrict__ xg) {
    __shared__ __align__(16) u16 Al[4096];
    __shared__ __align__(16) u16 Bl[4096];
    int tid = threadIdx.x;
    int lane = tid & 63, w = tid >> 6;
    int l16 = lane & 15, q = lane >> 4;
    int m0 = blockIdx.x * 128, n0 = blockIdx.y * 128;
    int mtb = (w & 1) * 4, ntb = (w >> 1) * 4;
    f32x4 acc[4][4];
    for (int a = 0; a < 4; ++a)
        for (int bb = 0; bb < 4; ++bb)
            for (int r = 0; r < 4; ++r) acc[a][bb][r] = 0.f;
    for (int kk = 0; kk < 16; ++kk) {
        int kb = kk * 32;
        __syncthreads();
        for (int i = 0; i < 2; ++i) {
            int wbase = i * 256 + w * 64;
            int slot = wbase + lane;
            int aq = slot >> 7, am = slot & 127;
            gload_lds16(xsb + (size_t)(m0 + am) * 512 + kb + aq * 8, Al + wbase * 8);
            gload_lds16(wcat + (size_t)(n0 + am) * 512 + kb + aq * 8, Bl + wbase * 8);
        }
        __syncthreads();
        bf16x8 af[4], bfr[4];
#pragma unroll
        for (int mt = 0; mt < 4; ++mt) af[mt] = *(const bf16x8*)(Al + (q * 128 + (mtb + mt) * 16 + l16) * 8);
#pragma unroll
        for (int nt = 0; nt < 4; ++nt) bfr[nt] = *(const bf16x8*)(Bl + (q * 128 + (ntb + nt) * 16 + l16) * 8);
#pragma unroll
        for (int mt = 0; mt < 4; ++mt)
#pragma unroll
            for (int nt = 0; nt < 4; ++nt)
                acc[mt][nt] = __builtin_amdgcn_mfma_f32_16x16x32_bf16(af[mt], bfr[nt], acc[mt][nt], 0, 0, 0);
    }
    float bias[4];
    for (int nt = 0; nt < 4; ++nt) {
        int gn = n0 + (ntb + nt) * 16 + l16;
        int rr = gn & 2047;
        bias[nt] = (gn >> 11) ? (bihb[rr] + bhhb[rr]) : (bihf[rr] + bhhf[rr]);
    }
    for (int mt = 0; mt < 4; ++mt)
        for (int nt = 0; nt < 4; ++nt)
            for (int r = 0; r < 4; ++r) {
                int gm = m0 + (mtb + mt) * 16 + q * 4 + r;
                int gn = n0 + (ntb + nt) * 16 + l16;
                xg[(size_t)gm * 4096 + gn] = f2bf(acc[mt][nt][r] + bias[nt]);
            }
}

// ---------------------------------------------------------------------------
// K2: persistent bidirectional LSTM. 64 blocks x 512 threads (32 per dir),
// R5's gate-split structure, verbatim, EXCEPT the release protocol:
//  - counter atomicAdd (32 serialized RMWs on one line) -> 32 per-producer
//    plain sc0sc1 flag stores on DISJOINT 64B lines.
//  - all-thread same-line counter poll -> each lane polls flag (lane&31);
//    one wave covers all 32 producers in a single parallel load round.
// Producer ordering: h stores -> vmcnt ack -> barrier C -> tid0 flag store.
// Consumer: observe all flags >= s+1, then (next loop top) load h rows.
// Flag-then-load through the single coherence point gives the same
// visibility guarantee the R5 counter relied on.
// ---------------------------------------------------------------------------
__global__ __launch_bounds__(512) void k_lstm(const u16* __restrict__ xg,
        const float* __restrict__ whhf, const float* __restrict__ whhb,
        u16* __restrict__ hf, u16* __restrict__ hb, unsigned* __restrict__ ctl) {
    __shared__ __align__(16) u16 hlds[32768];   // 64 KB
    __shared__ float gbuf[64 * 65];             // 16.6 KB
    int tid = threadIdx.x;
    int lane = tid & 63, w = tid >> 6;
    int l16 = lane & 15, q = lane >> 4;
    int dir = blockIdx.x >> 5, blk = blockIdx.x & 31;
    int j0 = blk * 16;
    const float* whh = dir ? whhb : whhf;
    u16* hbuf = dir ? hb : hf;
    unsigned* flags = ctl + dir * 512;          // 32 flags x 64B per dir
    const unsigned* myflag = flags + (lane & 31) * 16;
    // register-resident W_hh fragments: wave (w&3) owns local gate rows
    // 16*(w&3)..+15 (waves 4-7 duplicate, handling batch rows 32-63)
    int nloc = 16 * (w & 3) + l16;       // 0..63
    int gate = nloc >> 4, jl = nloc & 15;
    int grow = gate * 512 + j0 + jl;
    int mtb = (w >> 2) * 2;              // batch tile base: 0 or 2
    bf16x8 wf[16];
    for (int kc = 0; kc < 16; ++kc) {
        const float* sp = whh + (size_t)grow * 512 + kc * 32 + q * 8;
        float4 a = *(const float4*)sp;
        float4 b4 = *(const float4*)(sp + 4);
        bf16x8 tv;
        tv[0] = (short)f2bf(a.x);  tv[1] = (short)f2bf(a.y);
        tv[2] = (short)f2bf(a.z);  tv[3] = (short)f2bf(a.w);
        tv[4] = (short)f2bf(b4.x); tv[5] = (short)f2bf(b4.y);
        tv[6] = (short)f2bf(b4.z); tv[7] = (short)f2bf(b4.w);
        wf[kc] = tv;
    }
    int b = tid >> 3, jc = (tid & 7) << 1;  // update-phase: 2 cols per thread
    float cst[2] = {0.f, 0.f};
    // preload xg for step 0 (4 gates x 2 cols)
    ushort2 xv0, xv1, xv2, xv3;
    {
        int t = dir ? 511 : 0;
        const u16* xgr = xg + ((size_t)(t * 64 + b)) * 4096 + dir * 2048 + j0 + jc;
        xv0 = *(const ushort2*)(xgr);
        xv1 = *(const ushort2*)(xgr + 512);
        xv2 = *(const ushort2*)(xgr + 1024);
        xv3 = *(const ushort2*)(xgr + 1536);
    }
    for (int s = 0; s < 512; ++s) {
        int t = dir ? (511 - s) : s;
        f32x4 acc[2];
        if (s > 0) {
            // --- stage full h_prev -> LDS: coalesced 1KB rows, swizzled ---
            int tp = dir ? (t + 1) : (t - 1);
            const u16* hsrc = hbuf + (size_t)tp * 32768;
            uint4 rv[8];
#pragma unroll
            for (int it = 0; it < 8; ++it) {
                int cr = it * 8 + w;  // batch row
                rv[it] = loadh_cc(hsrc + (size_t)cr * 512 + lane * 8);
            }
            waitcnt0();
#pragma unroll
            for (int it = 0; it < 8; ++it) {
                int cr = it * 8 + w;
                int ps = lane * 64 + (cr ^ lane);  // kcq = lane
                *(uint4*)(hlds + (size_t)ps * 8) = rv[it];
            }
            __syncthreads();  // (A) staging visible
#pragma unroll
            for (int mi = 0; mi < 2; ++mi)
                for (int r = 0; r < 4; ++r) acc[mi][r] = 0.f;
#pragma unroll
            for (int kc = 0; kc < 16; ++kc) {
                int kcq = kc * 4 + q;
#pragma unroll
                for (int mi = 0; mi < 2; ++mi) {
                    int m = (mtb + mi) * 16 + l16;
                    bf16x8 a = *(const bf16x8*)(hlds + (size_t)(kcq * 64 + (m ^ kcq)) * 8);
                    acc[mi] = __builtin_amdgcn_mfma_f32_16x16x32_bf16(a, wf[kc], acc[mi], 0, 0, 0);
                }
            }
            for (int mi = 0; mi < 2; ++mi)
                for (int r = 0; r < 4; ++r)
                    gbuf[nloc * 65 + (mtb + mi) * 16 + q * 4 + r] = acc[mi][r];
            __syncthreads();  // (B) gates visible
        }
        // --- elementwise gate update (2 cells per thread) ---
        float hv[2];
        const u16* x0 = (const u16*)&xv0;
        const u16* x1 = (const u16*)&xv1;
        const u16* x2 = (const u16*)&xv2;
        const u16* x3 = (const u16*)&xv3;
#pragma unroll
        for (int p = 0; p < 2; ++p) {
            int jj = jc + p;
            float gi = bf2f(x0[p]);
            float gf = bf2f(x1[p]);
            float gg = bf2f(x2[p]);
            float go = bf2f(x3[p]);
            if (s > 0) {
                gi += gbuf[jj * 65 + b];
                gf += gbuf[(16 + jj) * 65 + b];
                gg += gbuf[(32 + jj) * 65 + b];
                go += gbuf[(48 + jj) * 65 + b];
            }
            float cc = sigf(gf) * cst[p] + sigf(gi) * tanhf_(gg);
            cst[p] = cc;
            hv[p] = sigf(go) * tanhf_(cc);
        }
        unsigned pk = (unsigned)f2bf(hv[0]) | ((unsigned)f2bf(hv[1]) << 16);
        storeh1_cc(hbuf + ((size_t)(t * 64 + b)) * 512 + j0 + jc, pk);
        waitcnt0();       // own h stores at coherence point
        __syncthreads();  // (C) whole block's h stores done
        if (s < 511) {
            if (tid == 0) storeflag_cc(flags + blk * 16, (unsigned)(s + 1));
            // prefetch next step's xg into the wait window (normal cached loads)
            int tn = dir ? (t - 1) : (t + 1);
            const u16* xgr = xg + ((size_t)(tn * 64 + b)) * 4096 + dir * 2048 + j0 + jc;
            xv0 = *(const ushort2*)(xgr);
            xv1 = *(const ushort2*)(xgr + 512);
            xv2 = *(const ushort2*)(xgr + 1024);
            xv3 = *(const ushort2*)(xgr + 1536);
            // wave-parallel detect: lane l polls producer flag (l&31);
            // one load round covers all 32 producers (disjoint 64B lines)
            unsigned tgt = (unsigned)(s + 1);
            for (;;) {
                unsigned v = loadflag_cc(myflag);
                if (__ballot(v < tgt) == 0ull) break;
                __builtin_amdgcn_s_sleep(1);
            }
            // per-wave exit; no extra block barrier needed (A resyncs)
        }
    }
}

// ---------------------------------------------------------------------------
// K3: em[m][21] = [hf[m], hb[m]] @ wlp^T + b_lin   (f32 out)
// ---------------------------------------------------------------------------
__global__ __launch_bounds__(256) void k_em(const u16* __restrict__ hf, const u16* __restrict__ hb,
        const u16* __restrict__ wlp, const float* __restrict__ blin, float* __restrict__ em) {
    __shared__ __align__(16) u16 Al[4096];
    __shared__ __align__(16) u16 Bl[1024];
    int tid = threadIdx.x;
    int lane = tid & 63, w = tid >> 6;
    int l16 = lane & 15, q = lane >> 4;
    int m0 = blockIdx.x * 128;
    f32x4 acc[2][2];
    for (int a = 0; a < 2; ++a)
        for (int bb = 0; bb < 2; ++bb)
            for (int r = 0; r < 4; ++r) acc[a][bb][r] = 0.f;
    for (int kc = 0; kc < 32; ++kc) {
        __syncthreads();
        for (int i = 0; i < 2; ++i) {
            int wbase = i * 256 + w * 64;
            int slot = wbase + lane;
            int aq = slot >> 7, am = slot & 127;
            int k = kc * 32 + aq * 8;
            const u16* src = (k < 512) ? (hf + (size_t)(m0 + am) * 512 + k)
                                       : (hb + (size_t)(m0 + am) * 512 + (k - 512));
            gload_lds16(src, Al + wbase * 8);
        }
        if (w < 2) {
            int slot = tid;
            int bq = slot >> 5, bn = slot & 31;
            gload_lds16(wlp + (size_t)bn * 1024 + kc * 32 + bq * 8, Bl + w * 64 * 8);
        }
        __syncthreads();
        bf16x8 af[2], bfr[2];
#pragma unroll
        for (int mi = 0; mi < 2; ++mi) af[mi] = *(const bf16x8*)(Al + (q * 128 + (w * 2 + mi) * 16 + l16) * 8);
#pragma unroll
        for (int ni = 0; ni < 2; ++ni) bfr[ni] = *(const bf16x8*)(Bl + (q * 32 + ni * 16 + l16) * 8);
#pragma unroll
        for (int mi = 0; mi < 2; ++mi)
#pragma unroll
            for (int ni = 0; ni < 2; ++ni)
                acc[mi][ni] = __builtin_amdgcn_mfma_f32_16x16x32_bf16(af[mi], bfr[ni], acc[mi][ni], 0, 0, 0);
    }
    for (int mi = 0; mi < 2; ++mi)
        for (int ni = 0; ni < 2; ++ni)
            for (int r = 0; r < 4; ++r) {
                int gm = m0 + (w * 2 + mi) * 16 + q * 4 + r;
                int tag = ni * 16 + l16;
                if (tag < 21) em[(size_t)gm * 21 + tag] = acc[mi][ni][r] + blin[tag];
            }
}

// ---------------------------------------------------------------------------
// K4: CRF forward + numerator. One wave per batch element.
// ---------------------------------------------------------------------------
__global__ __launch_bounds__(64) void k_crf(const float* __restrict__ em, const int* __restrict__ y,
        const int* __restrict__ sl, const float* __restrict__ st, const float* __restrict__ en,
        const float* __restrict__ tr, float* __restrict__ out) {
    int b = blockIdx.x;
    int j = threadIdx.x;
    bool act = j < 21;
    int seqlen = sl[b];
    float E[21];
    for (int i = 0; i < 21; ++i) E[i] = act ? __expf(tr[i * 21 + j]) : 1.0f;
    float alpha = act ? (st[j] + em[(size_t)b * 21 + j]) : -1e30f;
    float endv = act ? en[j] : 0.0f;
    float num = 0.0f;
    int tagp = 0;
    if (j == 0) {
        int t0 = y[b * 512];
        num = st[t0] + em[(size_t)b * 21 + t0];
        tagp = t0;
    }
    for (int t = 1; t < 512; ++t) {
        bool m = t < seqlen;
        float emv = act ? em[((size_t)t * 64 + b) * 21 + j] : 0.0f;
        float mx = alpha;
        for (int o = 16; o > 0; o >>= 1) mx = fmaxf(mx, __shfl_xor(mx, o, 32));
        float e = __expf(alpha - mx);
        float s = 0.0f;
#pragma unroll
        for (int i = 0; i < 21; ++i) s += __shfl(e, i) * E[i];
        float nxt = mx + __logf(s) + emv;
        if (m && act) alpha = nxt;
        if (m && j == 0) {
            int tc = y[b * 512 + t];
            num += tr[tagp * 21 + tc] + em[((size_t)t * 64 + b) * 21 + tc];
            tagp = tc;
        }
    }
    if (j == 0) num += en[y[b * 512 + seqlen - 1]];
    float v = act ? (alpha + endv) : -1e30f;
    float mz = v;
    for (int o = 16; o > 0; o >>= 1) mz = fmaxf(mz, __shfl_xor(mz, o, 32));
    float ez = act ? __expf(v - mz) : 0.0f;
    for (int o = 16; o > 0; o >>= 1) ez += __shfl_xor(ez, o, 32);
    float logZ = mz + __logf(ez);
    if (j == 0) atomicAdd(out, logZ - num);
}

__global__ void k_sentinel(float* out) {
    if (threadIdx.x == 0 && blockIdx.x == 0) out[0] = 123456.0f;
}

// ---------------------------------------------------------------------------
extern "C" void kernel_launch(void* const* d_in, const int* in_sizes, int n_in,
                              void* d_out, int out_size, void* d_ws, size_t ws_size,
                              hipStream_t stream) {
    const int*   x    = (const int*)d_in[0];
    const int*   y    = (const int*)d_in[1];
    const int*   sl   = (const int*)d_in[2];
    const float* emb  = (const float*)d_in[3];
    const float* wihf = (const float*)d_in[4];
    const float* whhf = (const float*)d_in[5];
    const float* bihf = (const float*)d_in[6];
    const float* bhhf = (const float*)d_in[7];
    const float* wihb = (const float*)d_in[8];
    const float* whhb = (const float*)d_in[9];
    const float* bihb = (const float*)d_in[10];
    const float* bhhb = (const float*)d_in[11];
    const float* wlin = (const float*)d_in[12];
    const float* blin = (const float*)d_in[13];
    const float* st   = (const float*)d_in[14];
    const float* en   = (const float*)d_in[15];
    const float* tr   = (const float*)d_in[16];

    const size_t OFF_XG   = 0;
    const size_t OFF_XSB  = 268435456;
    const size_t OFF_WCAT = 301989888;
    const size_t OFF_HF   = 306184192;
    const size_t OFF_HB   = 339738624;
    const size_t OFF_EM   = 373293056;
    const size_t OFF_WLP  = 376045568;
    const size_t OFF_CNT  = 376111104;
    const size_t NEEDED   = OFF_CNT + 4096;

    if (ws_size < NEEDED) {
        k_sentinel<<<1, 64, 0, stream>>>((float*)d_out);
        return;
    }
    char* ws = (char*)d_ws;
    u16*      xg   = (u16*)(ws + OFF_XG);
    u16*      xsb  = (u16*)(ws + OFF_XSB);
    u16*      wcat = (u16*)(ws + OFF_WCAT);
    u16*      hf   = (u16*)(ws + OFF_HF);
    u16*      hb   = (u16*)(ws + OFF_HB);
    float*    em   = (float*)(ws + OFF_EM);
    u16*      wlp  = (u16*)(ws + OFF_WLP);
    unsigned* ctl  = (unsigned*)(ws + OFF_CNT);

    hipMemsetAsync(ctl, 0, 4096, stream);
    hipMemsetAsync(d_out, 0, sizeof(float), stream);

    k_prep<<<9232, 256, 0, stream>>>(x, emb, wihf, wihb, wlin, xsb, wcat, wlp);
    k_gemm_xg<<<dim3(256, 32), 256, 0, stream>>>(xsb, wcat, bihf, bhhf, bihb, bhhb, xg);
    k_lstm<<<64, 512, 0, stream>>>(xg, whhf, whhb, hf, hb, ctl);
    k_em<<<256, 256, 0, stream>>>(hf, hb, wlp, blin, em);
    k_crf<<<64, 64, 0, stream>>>(em, y, sl, st, en, tr, (float*)d_out);
}

// Round 8
// 2492.712 us; speedup vs baseline: 1.4190x; 1.1069x over previous
//
#include <hip/hip_runtime.h>
#include <cstdint>

typedef unsigned short u16;
typedef short bf16x8 __attribute__((ext_vector_type(8)));
typedef float f32x4 __attribute__((ext_vector_type(4)));

typedef const __attribute__((address_space(1))) unsigned int* gas1_t;
typedef __attribute__((address_space(3))) unsigned int* las3_t;

__device__ __forceinline__ float bf2f(u16 u) {
    union { unsigned u; float f; } v; v.u = ((unsigned)u) << 16; return v.f;
}
__device__ __forceinline__ u16 f2bf(float f) {
    union { float f; unsigned u; } v; v.f = f;
    return (u16)((v.u + 0x7FFFu + ((v.u >> 16) & 1u)) >> 16);
}
// global->LDS direct DMA, 16B per lane. LDS dest is wave-uniform base + lane*16.
__device__ __forceinline__ void gload_lds16(const void* g, void* l) {
    gas1_t gp = reinterpret_cast<gas1_t>(reinterpret_cast<uintptr_t>(g));
    las3_t lp = reinterpret_cast<las3_t>(static_cast<uint32_t>(reinterpret_cast<uintptr_t>(l)));
    __builtin_amdgcn_global_load_lds(gp, lp, 16, 0, 0);
}
__device__ __forceinline__ float sigf(float x) { return 1.0f / (1.0f + __expf(-x)); }
__device__ __forceinline__ float tanhf_(float x) { return 2.0f / (1.0f + __expf(-2.0f * x)) - 1.0f; }

// --- cross-XCD coherent ops (device coherence point, sc0 sc1) ---
__device__ __forceinline__ void storehs_cc(u16* p, unsigned v) {
    asm volatile("global_store_short %0, %1, off sc0 sc1" :: "v"(p), "v"(v) : "memory");
}
__device__ __forceinline__ uint4 loadh_cc(const u16* p) {
    uint4 r;
    asm volatile("global_load_dwordx4 %0, %1, off sc0 sc1" : "=v"(r) : "v"(p) : "memory");
    return r;
}
__device__ __forceinline__ unsigned loadflag_cc(const unsigned* p) {
    unsigned r;
    asm volatile("global_load_dword %0, %1, off sc0 sc1\n\ts_waitcnt vmcnt(0)"
                 : "=v"(r) : "v"(p) : "memory");
    return r;
}
__device__ __forceinline__ void storeflag_cc(unsigned* p, unsigned v) {
    asm volatile("global_store_dword %0, %1, off sc0 sc1" :: "v"(p), "v"(v) : "memory");
}
__device__ __forceinline__ void waitcnt0() {
    asm volatile("s_waitcnt vmcnt(0)" ::: "memory");
}

// ---------------------------------------------------------------------------
// K0: prep — gather embeddings -> xsb (bf16), convert W_ih_f|W_ih_b -> wcat,
//            W_lin (padded to 32 rows) -> wlp
// ---------------------------------------------------------------------------
__global__ __launch_bounds__(256) void k_prep(const int* __restrict__ x, const float* __restrict__ emb,
        const float* __restrict__ wihf, const float* __restrict__ wihb, const float* __restrict__ wlin,
        u16* __restrict__ xsb, u16* __restrict__ wcat, u16* __restrict__ wlp) {
    int gid = blockIdx.x * 256 + threadIdx.x;
    const float* src = nullptr;
    u16* dst = nullptr;
    bool zero = false;
    if (gid < 2097152) {
        int row = gid >> 6, k0 = (gid & 63) << 3;
        int t = row >> 6, b = row & 63;
        int tok = x[b * 512 + t];
        src = emb + (size_t)tok * 512 + k0;
        dst = xsb + (size_t)row * 512 + k0;
    } else if (gid < 2359296) {
        int wid = gid - 2097152;
        int n = wid >> 6, k0 = (wid & 63) << 3;
        src = (n < 2048) ? (wihf + (size_t)n * 512 + k0) : (wihb + (size_t)(n - 2048) * 512 + k0);
        dst = wcat + (size_t)n * 512 + k0;
    } else {
        int wid = gid - 2359296;
        int n = wid >> 7, k0 = (wid & 127) << 3;
        dst = wlp + (size_t)n * 1024 + k0;
        if (n < 21) src = wlin + (size_t)n * 1024 + k0; else zero = true;
    }
    uint4 ov;
    if (zero) {
        ov.x = ov.y = ov.z = ov.w = 0u;
    } else {
        float4 a = *(const float4*)src;
        float4 b4 = *(const float4*)(src + 4);
        ov.x = (unsigned)f2bf(a.x) | ((unsigned)f2bf(a.y) << 16);
        ov.y = (unsigned)f2bf(a.z) | ((unsigned)f2bf(a.w) << 16);
        ov.z = (unsigned)f2bf(b4.x) | ((unsigned)f2bf(b4.y) << 16);
        ov.w = (unsigned)f2bf(b4.z) | ((unsigned)f2bf(b4.w) << 16);
    }
    *(uint4*)dst = ov;
}

// ---------------------------------------------------------------------------
// K1: xg[m][4096] = xsb @ wcat^T + bias (bf16 out). 128x128 tile, BK=32.
// ---------------------------------------------------------------------------
__global__ __launch_bounds__(256) void k_gemm_xg(const u16* __restrict__ xsb, const u16* __restrict__ wcat,
        const float* __restrict__ bihf, const float* __restrict__ bhhf,
        const float* __restrict__ bihb, const float* __restrict__ bhhb,
        u16* __restrict__ xg) {
    __shared__ __align__(16) u16 Al[4096];
    __shared__ __align__(16) u16 Bl[4096];
    int tid = threadIdx.x;
    int lane = tid & 63, w = tid >> 6;
    int l16 = lane & 15, q = lane >> 4;
    int m0 = blockIdx.x * 128, n0 = blockIdx.y * 128;
    int mtb = (w & 1) * 4, ntb = (w >> 1) * 4;
    f32x4 acc[4][4];
    for (int a = 0; a < 4; ++a)
        for (int bb = 0; bb < 4; ++bb)
            for (int r = 0; r < 4; ++r) acc[a][bb][r] = 0.f;
    for (int kk = 0; kk < 16; ++kk) {
        int kb = kk * 32;
        __syncthreads();
        for (int i = 0; i < 2; ++i) {
            int wbase = i * 256 + w * 64;
            int slot = wbase + lane;
            int aq = slot >> 7, am = slot & 127;
            gload_lds16(xsb + (size_t)(m0 + am) * 512 + kb + aq * 8, Al + wbase * 8);
            gload_lds16(wcat + (size_t)(n0 + am) * 512 + kb + aq * 8, Bl + wbase * 8);
        }
        __syncthreads();
        bf16x8 af[4], bfr[4];
#pragma unroll
        for (int mt = 0; mt < 4; ++mt) af[mt] = *(const bf16x8*)(Al + (q * 128 + (mtb + mt) * 16 + l16) * 8);
#pragma unroll
        for (int nt = 0; nt < 4; ++nt) bfr[nt] = *(const bf16x8*)(Bl + (q * 128 + (ntb + nt) * 16 + l16) * 8);
#pragma unroll
        for (int mt = 0; mt < 4; ++mt)
#pragma unroll
            for (int nt = 0; nt < 4; ++nt)
                acc[mt][nt] = __builtin_amdgcn_mfma_f32_16x16x32_bf16(af[mt], bfr[nt], acc[mt][nt], 0, 0, 0);
    }
    float bias[4];
    for (int nt = 0; nt < 4; ++nt) {
        int gn = n0 + (ntb + nt) * 16 + l16;
        int rr = gn & 2047;
        bias[nt] = (gn >> 11) ? (bihb[rr] + bhhb[rr]) : (bihf[rr] + bhhf[rr]);
    }
    for (int mt = 0; mt < 4; ++mt)
        for (int nt = 0; nt < 4; ++nt)
            for (int r = 0; r < 4; ++r) {
                int gm = m0 + (mtb + mt) * 16 + q * 4 + r;
                int gn = n0 + (ntb + nt) * 16 + l16;
                xg[(size_t)gm * 4096 + gn] = f2bf(acc[mt][nt][r] + bias[nt]);
            }
}

// ---------------------------------------------------------------------------
// K2: persistent bidirectional LSTM. 128 blocks x 512 threads (64 per dir).
// Quarter-gate split vs R7: each block owns 8 j-columns (32 gate rows).
// Wave pairing: (w&1) selects gate-row half (16 rows), (w>>1) selects batch
// quarter (16 rows). Per-block MFMA and update VALU halve vs R7; the 64KB
// h_prev broadcast staging is a fixed cost and is unchanged.
// Protocol = R7 verbatim, scaled: 64 per-producer flags/dir on disjoint
// 64B lines; lane l polls flag l (one parallel load round per detect).
// ---------------------------------------------------------------------------
__global__ __launch_bounds__(512) void k_lstm(const u16* __restrict__ xg,
        const float* __restrict__ whhf, const float* __restrict__ whhb,
        u16* __restrict__ hf, u16* __restrict__ hb, unsigned* __restrict__ ctl) {
    __shared__ __align__(16) u16 hlds[32768];   // 64 KB
    __shared__ float gbuf[32 * 65];             // 8.3 KB
    int tid = threadIdx.x;
    int lane = tid & 63, w = tid >> 6;
    int l16 = lane & 15, q = lane >> 4;
    int dir = blockIdx.x >> 6, blk = blockIdx.x & 63;
    int j0 = blk * 8;
    const float* whh = dir ? whhb : whhf;
    u16* hbuf = dir ? hb : hf;
    unsigned* flags = ctl + dir * 1024;         // 64 flags x 64B per dir
    const unsigned* myflag = flags + lane * 16; // lane l polls producer l
    // register-resident W_hh fragments: wave (w&1) owns local gate rows
    // 16*(w&1)..+15 of the 32; (w>>1) = batch quarter (duplicated W).
    int nloc = 16 * (w & 1) + l16;       // 0..31
    int gate = nloc >> 3, jl = nloc & 7;
    int grow = gate * 512 + j0 + jl;
    int mtb = (w >> 1);                  // batch tile: 0..3 (16 rows each)
    bf16x8 wf[16];
    for (int kc = 0; kc < 16; ++kc) {
        const float* sp = whh + (size_t)grow * 512 + kc * 32 + q * 8;
        float4 a = *(const float4*)sp;
        float4 b4 = *(const float4*)(sp + 4);
        bf16x8 tv;
        tv[0] = (short)f2bf(a.x);  tv[1] = (short)f2bf(a.y);
        tv[2] = (short)f2bf(a.z);  tv[3] = (short)f2bf(a.w);
        tv[4] = (short)f2bf(b4.x); tv[5] = (short)f2bf(b4.y);
        tv[6] = (short)f2bf(b4.z); tv[7] = (short)f2bf(b4.w);
        wf[kc] = tv;
    }
    int b = tid >> 3, jc = tid & 7;      // update-phase: 1 cell per thread
    float cst = 0.f;
    // preload xg for step 0 (4 gates x 1 col)
    u16 xv0, xv1, xv2, xv3;
    {
        int t = dir ? 511 : 0;
        const u16* xgr = xg + ((size_t)(t * 64 + b)) * 4096 + dir * 2048 + j0 + jc;
        xv0 = xgr[0]; xv1 = xgr[512]; xv2 = xgr[1024]; xv3 = xgr[1536];
    }
    for (int s = 0; s < 512; ++s) {
        int t = dir ? (511 - s) : s;
        f32x4 acc;
        if (s > 0) {
            // --- stage full h_prev -> LDS: coalesced 1KB rows, swizzled ---
            int tp = dir ? (t + 1) : (t - 1);
            const u16* hsrc = hbuf + (size_t)tp * 32768;
            uint4 rv[8];
#pragma unroll
            for (int it = 0; it < 8; ++it) {
                int cr = it * 8 + w;  // batch row
                rv[it] = loadh_cc(hsrc + (size_t)cr * 512 + lane * 8);
            }
            waitcnt0();
#pragma unroll
            for (int it = 0; it < 8; ++it) {
                int cr = it * 8 + w;
                int ps = lane * 64 + (cr ^ lane);  // kcq = lane
                *(uint4*)(hlds + (size_t)ps * 8) = rv[it];
            }
            __syncthreads();  // (A) staging visible
            for (int r = 0; r < 4; ++r) acc[r] = 0.f;
#pragma unroll
            for (int kc = 0; kc < 16; ++kc) {
                int kcq = kc * 4 + q;
                int m = mtb * 16 + l16;
                bf16x8 a = *(const bf16x8*)(hlds + (size_t)(kcq * 64 + (m ^ kcq)) * 8);
                acc = __builtin_amdgcn_mfma_f32_16x16x32_bf16(a, wf[kc], acc, 0, 0, 0);
            }
            for (int r = 0; r < 4; ++r)
                gbuf[nloc * 65 + mtb * 16 + q * 4 + r] = acc[r];
            __syncthreads();  // (B) gates visible
        }
        // --- elementwise gate update (1 cell per thread) ---
        float gi = bf2f(xv0);
        float gf = bf2f(xv1);
        float gg = bf2f(xv2);
        float go = bf2f(xv3);
        if (s > 0) {
            gi += gbuf[jc * 65 + b];
            gf += gbuf[(8 + jc) * 65 + b];
            gg += gbuf[(16 + jc) * 65 + b];
            go += gbuf[(24 + jc) * 65 + b];
        }
        float cc = sigf(gf) * cst + sigf(gi) * tanhf_(gg);
        cst = cc;
        float hv = sigf(go) * tanhf_(cc);
        storehs_cc(hbuf + ((size_t)(t * 64 + b)) * 512 + j0 + jc, (unsigned)f2bf(hv));
        waitcnt0();       // own h store at coherence point
        __syncthreads();  // (C) whole block's h stores done
        if (s < 511) {
            if (tid == 0) storeflag_cc(flags + blk * 16, (unsigned)(s + 1));
            // prefetch next step's xg into the wait window (normal cached loads)
            int tn = dir ? (t - 1) : (t + 1);
            const u16* xgr = xg + ((size_t)(tn * 64 + b)) * 4096 + dir * 2048 + j0 + jc;
            xv0 = xgr[0]; xv1 = xgr[512]; xv2 = xgr[1024]; xv3 = xgr[1536];
            // wave-parallel detect: lane l polls producer flag l (64 flags,
            // disjoint 64B lines, one load round per poll)
            unsigned tgt = (unsigned)(s + 1);
            for (;;) {
                unsigned v = loadflag_cc(myflag);
                if (__ballot(v < tgt) == 0ull) break;
                __builtin_amdgcn_s_sleep(1);
            }
            // per-wave exit; no extra block barrier needed (A resyncs)
        }
    }
}

// ---------------------------------------------------------------------------
// K3: em[m][21] = [hf[m], hb[m]] @ wlp^T + b_lin   (f32 out)
// ---------------------------------------------------------------------------
__global__ __launch_bounds__(256) void k_em(const u16* __restrict__ hf, const u16* __restrict__ hb,
        const u16* __restrict__ wlp, const float* __restrict__ blin, float* __restrict__ em) {
    __shared__ __align__(16) u16 Al[4096];
    __shared__ __align__(16) u16 Bl[1024];
    int tid = threadIdx.x;
    int lane = tid & 63, w = tid >> 6;
    int l16 = lane & 15, q = lane >> 4;
    int m0 = blockIdx.x * 128;
    f32x4 acc[2][2];
    for (int a = 0; a < 2; ++a)
        for (int bb = 0; bb < 2; ++bb)
            for (int r = 0; r < 4; ++r) acc[a][bb][r] = 0.f;
    for (int kc = 0; kc < 32; ++kc) {
        __syncthreads();
        for (int i = 0; i < 2; ++i) {
            int wbase = i * 256 + w * 64;
            int slot = wbase + lane;
            int aq = slot >> 7, am = slot & 127;
            int k = kc * 32 + aq * 8;
            const u16* src = (k < 512) ? (hf + (size_t)(m0 + am) * 512 + k)
                                       : (hb + (size_t)(m0 + am) * 512 + (k - 512));
            gload_lds16(src, Al + wbase * 8);
        }
        if (w < 2) {
            int slot = tid;
            int bq = slot >> 5, bn = slot & 31;
            gload_lds16(wlp + (size_t)bn * 1024 + kc * 32 + bq * 8, Bl + w * 64 * 8);
        }
        __syncthreads();
        bf16x8 af[2], bfr[2];
#pragma unroll
        for (int mi = 0; mi < 2; ++mi) af[mi] = *(const bf16x8*)(Al + (q * 128 + (w * 2 + mi) * 16 + l16) * 8);
#pragma unroll
        for (int ni = 0; ni < 2; ++ni) bfr[ni] = *(const bf16x8*)(Bl + (q * 32 + ni * 16 + l16) * 8);
#pragma unroll
        for (int mi = 0; mi < 2; ++mi)
#pragma unroll
            for (int ni = 0; ni < 2; ++ni)
                acc[mi][ni] = __builtin_amdgcn_mfma_f32_16x16x32_bf16(af[mi], bfr[ni], acc[mi][ni], 0, 0, 0);
    }
    for (int mi = 0; mi < 2; ++mi)
        for (int ni = 0; ni < 2; ++ni)
            for (int r = 0; r < 4; ++r) {
                int gm = m0 + (w * 2 + mi) * 16 + q * 4 + r;
                int tag = ni * 16 + l16;
                if (tag < 21) em[(size_t)gm * 21 + tag] = acc[mi][ni][r] + blin[tag];
            }
}

// ---------------------------------------------------------------------------
// K4: CRF forward + numerator. One wave per batch element.
// ---------------------------------------------------------------------------
__global__ __launch_bounds__(64) void k_crf(const float* __restrict__ em, const int* __restrict__ y,
        const int* __restrict__ sl, const float* __restrict__ st, const float* __restrict__ en,
        const float* __restrict__ tr, float* __restrict__ out) {
    int b = blockIdx.x;
    int j = threadIdx.x;
    bool act = j < 21;
    int seqlen = sl[b];
    float E[21];
    for (int i = 0; i < 21; ++i) E[i] = act ? __expf(tr[i * 21 + j]) : 1.0f;
    float alpha = act ? (st[j] + em[(size_t)b * 21 + j]) : -1e30f;
    float endv = act ? en[j] : 0.0f;
    float num = 0.0f;
    int tagp = 0;
    if (j == 0) {
        int t0 = y[b * 512];
        num = st[t0] + em[(size_t)b * 21 + t0];
        tagp = t0;
    }
    for (int t = 1; t < 512; ++t) {
        bool m = t < seqlen;
        float emv = act ? em[((size_t)t * 64 + b) * 21 + j] : 0.0f;
        float mx = alpha;
        for (int o = 16; o > 0; o >>= 1) mx = fmaxf(mx, __shfl_xor(mx, o, 32));
        float e = __expf(alpha - mx);
        float s = 0.0f;
#pragma unroll
        for (int i = 0; i < 21; ++i) s += __shfl(e, i) * E[i];
        float nxt = mx + __logf(s) + emv;
        if (m && act) alpha = nxt;
        if (m && j == 0) {
            int tc = y[b * 512 + t];
            num += tr[tagp * 21 + tc] + em[((size_t)t * 64 + b) * 21 + tc];
            tagp = tc;
        }
    }
    if (j == 0) num += en[y[b * 512 + seqlen - 1]];
    float v = act ? (alpha + endv) : -1e30f;
    float mz = v;
    for (int o = 16; o > 0; o >>= 1) mz = fmaxf(mz, __shfl_xor(mz, o, 32));
    float ez = act ? __expf(v - mz) : 0.0f;
    for (int o = 16; o > 0; o >>= 1) ez += __shfl_xor(ez, o, 32);
    float logZ = mz + __logf(ez);
    if (j == 0) atomicAdd(out, logZ - num);
}

__global__ void k_sentinel(float* out) {
    if (threadIdx.x == 0 && blockIdx.x == 0) out[0] = 123456.0f;
}

// ---------------------------------------------------------------------------
extern "C" void kernel_launch(void* const* d_in, const int* in_sizes, int n_in,
                              void* d_out, int out_size, void* d_ws, size_t ws_size,
                              hipStream_t stream) {
    const int*   x    = (const int*)d_in[0];
    const int*   y    = (const int*)d_in[1];
    const int*   sl   = (const int*)d_in[2];
    const float* emb  = (const float*)d_in[3];
    const float* wihf = (const float*)d_in[4];
    const float* whhf = (const float*)d_in[5];
    const float* bihf = (const float*)d_in[6];
    const float* bhhf = (const float*)d_in[7];
    const float* wihb = (const float*)d_in[8];
    const float* whhb = (const float*)d_in[9];
    const float* bihb = (const float*)d_in[10];
    const float* bhhb = (const float*)d_in[11];
    const float* wlin = (const float*)d_in[12];
    const float* blin = (const float*)d_in[13];
    const float* st   = (const float*)d_in[14];
    const float* en   = (const float*)d_in[15];
    const float* tr   = (const float*)d_in[16];

    const size_t OFF_XG   = 0;
    const size_t OFF_XSB  = 268435456;
    const size_t OFF_WCAT = 301989888;
    const size_t OFF_HF   = 306184192;
    const size_t OFF_HB   = 339738624;
    const size_t OFF_EM   = 373293056;
    const size_t OFF_WLP  = 376045568;
    const size_t OFF_CNT  = 376111104;
    const size_t NEEDED   = OFF_CNT + 8192;

    if (ws_size < NEEDED) {
        k_sentinel<<<1, 64, 0, stream>>>((float*)d_out);
        return;
    }
    char* ws = (char*)d_ws;
    u16*      xg   = (u16*)(ws + OFF_XG);
    u16*      xsb  = (u16*)(ws + OFF_XSB);
    u16*      wcat = (u16*)(ws + OFF_WCAT);
    u16*      hf   = (u16*)(ws + OFF_HF);
    u16*      hb   = (u16*)(ws + OFF_HB);
    float*    em   = (float*)(ws + OFF_EM);
    u16*      wlp  = (u16*)(ws + OFF_WLP);
    unsigned* ctl  = (unsigned*)(ws + OFF_CNT);

    hipMemsetAsync(ctl, 0, 8192, stream);
    hipMemsetAsync(d_out, 0, sizeof(float), stream);

    k_prep<<<9232, 256, 0, stream>>>(x, emb, wihf, wihb, wlin, xsb, wcat, wlp);
    k_gemm_xg<<<dim3(256, 32), 256, 0, stream>>>(xsb, wcat, bihf, bhhf, bihb, bhhb, xg);
    k_lstm<<<128, 512, 0, stream>>>(xg, whhf, whhb, hf, hb, ctl);
    k_em<<<256, 256, 0, stream>>>(hf, hb, wlp, blin, em);
    k_crf<<<64, 64, 0, stream>>>(em, y, sl, st, en, tr, (float*)d_out);
}

// Round 10
// 2029.008 us; speedup vs baseline: 1.7433x; 1.2285x over previous
//
#include <hip/hip_runtime.h>
#include <cstdint>

typedef unsigned short u16;
typedef short bf16x8 __attribute__((ext_vector_type(8)));
typedef float f32x4 __attribute__((ext_vector_type(4)));

typedef const __attribute__((address_space(1))) unsigned int* gas1_t;
typedef __attribute__((address_space(3))) unsigned int* las3_t;

__device__ __forceinline__ float bf2f(u16 u) {
    union { unsigned u; float f; } v; v.u = ((unsigned)u) << 16; return v.f;
}
__device__ __forceinline__ u16 f2bf(float f) {
    union { float f; unsigned u; } v; v.f = f;
    return (u16)((v.u + 0x7FFFu + ((v.u >> 16) & 1u)) >> 16);
}
// global->LDS direct DMA, 16B per lane. LDS dest is wave-uniform base + lane*16.
__device__ __forceinline__ void gload_lds16(const void* g, void* l) {
    gas1_t gp = reinterpret_cast<gas1_t>(reinterpret_cast<uintptr_t>(g));
    las3_t lp = reinterpret_cast<las3_t>(static_cast<uint32_t>(reinterpret_cast<uintptr_t>(l)));
    __builtin_amdgcn_global_load_lds(gp, lp, 16, 0, 0);
}
__device__ __forceinline__ float sigf(float x) { return 1.0f / (1.0f + __expf(-x)); }
__device__ __forceinline__ float tanhf_(float x) { return 2.0f / (1.0f + __expf(-2.0f * x)) - 1.0f; }

// --- cross-XCD coherent ops (device coherence point, sc0 sc1) ---
__device__ __forceinline__ void storehs_cc(u16* p, unsigned v) {
    asm volatile("global_store_short %0, %1, off sc0 sc1" :: "v"(p), "v"(v) : "memory");
}
__device__ __forceinline__ uint4 loadh_cc(const u16* p) {
    uint4 r;
    asm volatile("global_load_dwordx4 %0, %1, off sc0 sc1" : "=v"(r) : "v"(p) : "memory");
    return r;
}
__device__ __forceinline__ unsigned loadflag_cc(const unsigned* p) {
    unsigned r;
    asm volatile("global_load_dword %0, %1, off sc0 sc1\n\ts_waitcnt vmcnt(0)"
                 : "=v"(r) : "v"(p) : "memory");
    return r;
}
__device__ __forceinline__ void storeflag_cc(unsigned* p, unsigned v) {
    asm volatile("global_store_dword %0, %1, off sc0 sc1" :: "v"(p), "v"(v) : "memory");
}
__device__ __forceinline__ void waitcnt0() {
    asm volatile("s_waitcnt vmcnt(0)" ::: "memory");
}

// ---------------------------------------------------------------------------
// K0: prep — gather embeddings -> xsb (bf16), convert W_ih_f|W_ih_b -> wcat,
//            W_lin (padded to 32 rows) -> wlp
// ---------------------------------------------------------------------------
__global__ __launch_bounds__(256) void k_prep(const int* __restrict__ x, const float* __restrict__ emb,
        const float* __restrict__ wihf, const float* __restrict__ wihb, const float* __restrict__ wlin,
        u16* __restrict__ xsb, u16* __restrict__ wcat, u16* __restrict__ wlp) {
    int gid = blockIdx.x * 256 + threadIdx.x;
    const float* src = nullptr;
    u16* dst = nullptr;
    bool zero = false;
    if (gid < 2097152) {
        int row = gid >> 6, k0 = (gid & 63) << 3;
        int t = row >> 6, b = row & 63;
        int tok = x[b * 512 + t];
        src = emb + (size_t)tok * 512 + k0;
        dst = xsb + (size_t)row * 512 + k0;
    } else if (gid < 2359296) {
        int wid = gid - 2097152;
        int n = wid >> 6, k0 = (wid & 63) << 3;
        src = (n < 2048) ? (wihf + (size_t)n * 512 + k0) : (wihb + (size_t)(n - 2048) * 512 + k0);
        dst = wcat + (size_t)n * 512 + k0;
    } else {
        int wid = gid - 2359296;
        int n = wid >> 7, k0 = (wid & 127) << 3;
        dst = wlp + (size_t)n * 1024 + k0;
        if (n < 21) src = wlin + (size_t)n * 1024 + k0; else zero = true;
    }
    uint4 ov;
    if (zero) {
        ov.x = ov.y = ov.z = ov.w = 0u;
    } else {
        float4 a = *(const float4*)src;
        float4 b4 = *(const float4*)(src + 4);
        ov.x = (unsigned)f2bf(a.x) | ((unsigned)f2bf(a.y) << 16);
        ov.y = (unsigned)f2bf(a.z) | ((unsigned)f2bf(a.w) << 16);
        ov.z = (unsigned)f2bf(b4.x) | ((unsigned)f2bf(b4.y) << 16);
        ov.w = (unsigned)f2bf(b4.z) | ((unsigned)f2bf(b4.w) << 16);
    }
    *(uint4*)dst = ov;
}

// ---------------------------------------------------------------------------
// K1: xg[m][4096] = xsb @ wcat^T + bias (bf16 out). 128x128 tile, BK=32.
// ---------------------------------------------------------------------------
__global__ __launch_bounds__(256) void k_gemm_xg(const u16* __restrict__ xsb, const u16* __restrict__ wcat,
        const float* __restrict__ bihf, const float* __restrict__ bhhf,
        const float* __restrict__ bihb, const float* __restrict__ bhhb,
        u16* __restrict__ xg) {
    __shared__ __align__(16) u16 Al[4096];
    __shared__ __align__(16) u16 Bl[4096];
    int tid = threadIdx.x;
    int lane = tid & 63, w = tid >> 6;
    int l16 = lane & 15, q = lane >> 4;
    int m0 = blockIdx.x * 128, n0 = blockIdx.y * 128;
    int mtb = (w & 1) * 4, ntb = (w >> 1) * 4;
    f32x4 acc[4][4];
    for (int a = 0; a < 4; ++a)
        for (int bb = 0; bb < 4; ++bb)
            for (int r = 0; r < 4; ++r) acc[a][bb][r] = 0.f;
    for (int kk = 0; kk < 16; ++kk) {
        int kb = kk * 32;
        __syncthreads();
        for (int i = 0; i < 2; ++i) {
            int wbase = i * 256 + w * 64;
            int slot = wbase + lane;
            int aq = slot >> 7, am = slot & 127;
            gload_lds16(xsb + (size_t)(m0 + am) * 512 + kb + aq * 8, Al + wbase * 8);
            gload_lds16(wcat + (size_t)(n0 + am) * 512 + kb + aq * 8, Bl + wbase * 8);
        }
        __syncthreads();
        bf16x8 af[4], bfr[4];
#pragma unroll
        for (int mt = 0; mt < 4; ++mt) af[mt] = *(const bf16x8*)(Al + (q * 128 + (mtb + mt) * 16 + l16) * 8);
#pragma unroll
        for (int nt = 0; nt < 4; ++nt) bfr[nt] = *(const bf16x8*)(Bl + (q * 128 + (ntb + nt) * 16 + l16) * 8);
#pragma unroll
        for (int mt = 0; mt < 4; ++mt)
#pragma unroll
            for (int nt = 0; nt < 4; ++nt)
                acc[mt][nt] = __builtin_amdgcn_mfma_f32_16x16x32_bf16(af[mt], bfr[nt], acc[mt][nt], 0, 0, 0);
    }
    float bias[4];
    for (int nt = 0; nt < 4; ++nt) {
        int gn = n0 + (ntb + nt) * 16 + l16;
        int rr = gn & 2047;
        bias[nt] = (gn >> 11) ? (bihb[rr] + bhhb[rr]) : (bihf[rr] + bhhf[rr]);
    }
    for (int mt = 0; mt < 4; ++mt)
        for (int nt = 0; nt < 4; ++nt)
            for (int r = 0; r < 4; ++r) {
                int gm = m0 + (mtb + mt) * 16 + q * 4 + r;
                int gn = n0 + (ntb + nt) * 16 + l16;
                xg[(size_t)gm * 4096 + gn] = f2bf(acc[mt][nt][r] + bias[nt]);
            }
}

// ---------------------------------------------------------------------------
// K2: persistent bidirectional LSTM. 128 blocks x 512 threads.
// 2-D decomposition: per dir, 4 batch-groups (bg) x 16 j-groups (jg).
// Block (dir,bg,jg) computes h[t][batch 16bg..+16][j 32jg..+32]:
//  - stages only h_prev[its 16 batch rows][512] = 16 KB (was 64 KB),
//  - depends only on the 16 producers (dir,bg,*): 8 independent sync
//    groups of 16 blocks each (smaller straggler max, 16-flag detect).
// Per wave: 16 distinct gate rows (128/block), M=16 exact, 16 MFMA.
// Protocol = R8 verbatim: disjoint-line flags, store->ack->barC->flag,
// wave-parallel poll (lane&15 -> flag (bg,lane&15)).
// ---------------------------------------------------------------------------
__global__ __launch_bounds__(512) void k_lstm(const u16* __restrict__ xg,
        const float* __restrict__ whhf, const float* __restrict__ whhb,
        u16* __restrict__ hf, u16* __restrict__ hb, unsigned* __restrict__ ctl) {
    __shared__ __align__(16) u16 hlds[8192];    // 16 KB: [kcq 0..63][m 0..15] x 8 u16
    __shared__ float gbuf[128 * 17];            // 8.7 KB: [gate row][batch 16 + pad]
    int tid = threadIdx.x;
    int lane = tid & 63, w = tid >> 6;
    int l16 = lane & 15, q = lane >> 4;
    int dir = blockIdx.x >> 6;
    int rest = blockIdx.x & 63;
    int bg = rest >> 4, jg = rest & 15;
    int j0 = jg * 32;
    int b0 = bg * 16;
    const float* whh = dir ? whhb : whhf;
    u16* hbuf = dir ? hb : hf;
    unsigned* flags = ctl + dir * 1024;          // 64 flags x 64B per dir
    const unsigned* myflag = flags + (bg * 16 + (lane & 15)) * 16;
    // register-resident W_hh fragments: wave w owns gate rows w*16..+15 of
    // the block's 128 (gate = nloc>>5, col-within-H = j0 + (nloc&31))
    int nloc = w * 16 + l16;             // 0..127
    int gate = nloc >> 5, jl = nloc & 31;
    int grow = gate * 512 + j0 + jl;
    bf16x8 wf[16];
    for (int kc = 0; kc < 16; ++kc) {
        const float* sp = whh + (size_t)grow * 512 + kc * 32 + q * 8;
        float4 a = *(const float4*)sp;
        float4 b4 = *(const float4*)(sp + 4);
        bf16x8 tv;
        tv[0] = (short)f2bf(a.x);  tv[1] = (short)f2bf(a.y);
        tv[2] = (short)f2bf(a.z);  tv[3] = (short)f2bf(a.w);
        tv[4] = (short)f2bf(b4.x); tv[5] = (short)f2bf(b4.y);
        tv[6] = (short)f2bf(b4.z); tv[7] = (short)f2bf(b4.w);
        wf[kc] = tv;
    }
    int bl = tid >> 5, jc = tid & 31;    // update: batch-local 0..15, col 0..31
    int bglob = b0 + bl;
    float cst = 0.f;
    // preload xg for step 0 (4 gates x 1 col)
    u16 xv0, xv1, xv2, xv3;
    {
        int t = dir ? 511 : 0;
        const u16* xgr = xg + ((size_t)(t * 64 + bglob)) * 4096 + dir * 2048 + j0 + jc;
        xv0 = xgr[0]; xv1 = xgr[512]; xv2 = xgr[1024]; xv3 = xgr[1536];
    }
    for (int s = 0; s < 512; ++s) {
        int t = dir ? (511 - s) : s;
        f32x4 acc;
        if (s > 0) {
            // --- stage h_prev[16 rows][512] -> LDS: 2 coalesced rounds ---
            int tp = dir ? (t + 1) : (t - 1);
            const u16* hsrc = hbuf + (size_t)(tp * 64 + b0) * 512;
            uint4 rv[2];
#pragma unroll
            for (int it = 0; it < 2; ++it) {
                int cr = it * 8 + w;  // batch-local row 0..15
                rv[it] = loadh_cc(hsrc + (size_t)cr * 512 + lane * 8);
            }
            waitcnt0();
#pragma unroll
            for (int it = 0; it < 2; ++it) {
                int cr = it * 8 + w;
                int ps = lane * 16 + (cr ^ (lane & 15));  // kcq = lane
                *(uint4*)(hlds + (size_t)ps * 8) = rv[it];
            }
            __syncthreads();  // (A) staging visible
            for (int r = 0; r < 4; ++r) acc[r] = 0.f;
#pragma unroll
            for (int kc = 0; kc < 16; ++kc) {
                int kcq = kc * 4 + q;
                bf16x8 a = *(const bf16x8*)(hlds + (size_t)(kcq * 16 + (l16 ^ (kcq & 15))) * 8);
                acc = __builtin_amdgcn_mfma_f32_16x16x32_bf16(a, wf[kc], acc, 0, 0, 0);
            }
            for (int r = 0; r < 4; ++r)
                gbuf[nloc * 17 + q * 4 + r] = acc[r];
            __syncthreads();  // (B) gates visible
        }
        // --- elementwise gate update (1 cell per thread) ---
        float gi = bf2f(xv0);
        float gf = bf2f(xv1);
        float gg = bf2f(xv2);
        float go = bf2f(xv3);
        if (s > 0) {
            gi += gbuf[(jc) * 17 + bl];
            gf += gbuf[(32 + jc) * 17 + bl];
            gg += gbuf[(64 + jc) * 17 + bl];
            go += gbuf[(96 + jc) * 17 + bl];
        }
        float cc = sigf(gf) * cst + sigf(gi) * tanhf_(gg);
        cst = cc;
        float hv = sigf(go) * tanhf_(cc);
        storehs_cc(hbuf + ((size_t)(t * 64 + bglob)) * 512 + j0 + jc, (unsigned)f2bf(hv));
        waitcnt0();       // own h store at coherence point
        __syncthreads();  // (C) whole block's h stores done
        if (s < 511) {
            if (tid == 0) storeflag_cc(flags + (bg * 16 + jg) * 16, (unsigned)(s + 1));
            // prefetch next step's xg into the wait window (normal cached loads)
            int tn = dir ? (t - 1) : (t + 1);
            const u16* xgr = xg + ((size_t)(tn * 64 + bglob)) * 4096 + dir * 2048 + j0 + jc;
            xv0 = xgr[0]; xv1 = xgr[512]; xv2 = xgr[1024]; xv3 = xgr[1536];
            // wave-parallel detect: lane polls flag (bg, lane&15); only the
            // 16 producers of this (dir,bg) group matter.
            unsigned tgt = (unsigned)(s + 1);
            for (;;) {
                unsigned v = loadflag_cc(myflag);
                if (__ballot(v < tgt) == 0ull) break;
                __builtin_amdgcn_s_sleep(1);
            }
            // per-wave exit; no extra block barrier needed (A resyncs)
        }
    }
}

// ---------------------------------------------------------------------------
// K3: em[m][21] = [hf[m], hb[m]] @ wlp^T + b_lin   (f32 out)
// ---------------------------------------------------------------------------
__global__ __launch_bounds__(256) void k_em(const u16* __restrict__ hf, const u16* __restrict__ hb,
        const u16* __restrict__ wlp, const float* __restrict__ blin, float* __restrict__ em) {
    __shared__ __align__(16) u16 Al[4096];
    __shared__ __align__(16) u16 Bl[1024];
    int tid = threadIdx.x;
    int lane = tid & 63, w = tid >> 6;
    int l16 = lane & 15, q = lane >> 4;
    int m0 = blockIdx.x * 128;
    f32x4 acc[2][2];
    for (int a = 0; a < 2; ++a)
        for (int bb = 0; bb < 2; ++bb)
            for (int r = 0; r < 4; ++r) acc[a][bb][r] = 0.f;
    for (int kc = 0; kc < 32; ++kc) {
        __syncthreads();
        for (int i = 0; i < 2; ++i) {
            int wbase = i * 256 + w * 64;
            int slot = wbase + lane;
            int aq = slot >> 7, am = slot & 127;
            int k = kc * 32 + aq * 8;
            const u16* src = (k < 512) ? (hf + (size_t)(m0 + am) * 512 + k)
                                       : (hb + (size_t)(m0 + am) * 512 + (k - 512));
            gload_lds16(src, Al + wbase * 8);
        }
        if (w < 2) {
            int slot = tid;
            int bq = slot >> 5, bn = slot & 31;
            gload_lds16(wlp + (size_t)bn * 1024 + kc * 32 + bq * 8, Bl + w * 64 * 8);
        }
        __syncthreads();
        bf16x8 af[2], bfr[2];
#pragma unroll
        for (int mi = 0; mi < 2; ++mi) af[mi] = *(const bf16x8*)(Al + (q * 128 + (w * 2 + mi) * 16 + l16) * 8);
#pragma unroll
        for (int ni = 0; ni < 2; ++ni) bfr[ni] = *(const bf16x8*)(Bl + (q * 32 + ni * 16 + l16) * 8);
#pragma unroll
        for (int mi = 0; mi < 2; ++mi)
#pragma unroll
            for (int ni = 0; ni < 2; ++ni)
                acc[mi][ni] = __builtin_amdgcn_mfma_f32_16x16x32_bf16(af[mi], bfr[ni], acc[mi][ni], 0, 0, 0);
    }
    for (int mi = 0; mi < 2; ++mi)
        for (int ni = 0; ni < 2; ++ni)
            for (int r = 0; r < 4; ++r) {
                int gm = m0 + (w * 2 + mi) * 16 + q * 4 + r;
                int tag = ni * 16 + l16;
                if (tag < 21) em[(size_t)gm * 21 + tag] = acc[mi][ni][r] + blin[tag];
            }
}

// ---------------------------------------------------------------------------
// K4: CRF forward + numerator. One wave per batch element.
// ---------------------------------------------------------------------------
__global__ __launch_bounds__(64) void k_crf(const float* __restrict__ em, const int* __restrict__ y,
        const int* __restrict__ sl, const float* __restrict__ st, const float* __restrict__ en,
        const float* __restrict__ tr, float* __restrict__ out) {
    int b = blockIdx.x;
    int j = threadIdx.x;
    bool act = j < 21;
    int seqlen = sl[b];
    float E[21];
    for (int i = 0; i < 21; ++i) E[i] = act ? __expf(tr[i * 21 + j]) : 1.0f;
    float alpha = act ? (st[j] + em[(size_t)b * 21 + j]) : -1e30f;
    float endv = act ? en[j] : 0.0f;
    float num = 0.0f;
    int tagp = 0;
    if (j == 0) {
        int t0 = y[b * 512];
        num = st[t0] + em[(size_t)b * 21 + t0];
        tagp = t0;
    }
    for (int t = 1; t < 512; ++t) {
        bool m = t < seqlen;
        float emv = act ? em[((size_t)t * 64 + b) * 21 + j] : 0.0f;
        float mx = alpha;
        for (int o = 16; o > 0; o >>= 1) mx = fmaxf(mx, __shfl_xor(mx, o, 32));
        float e = __expf(alpha - mx);
        float s = 0.0f;
#pragma unroll
        for (int i = 0; i < 21; ++i) s += __shfl(e, i) * E[i];
        float nxt = mx + __logf(s) + emv;
        if (m && act) alpha = nxt;
        if (m && j == 0) {
            int tc = y[b * 512 + t];
            num += tr[tagp * 21 + tc] + em[((size_t)t * 64 + b) * 21 + tc];
            tagp = tc;
        }
    }
    if (j == 0) num += en[y[b * 512 + seqlen - 1]];
    float v = act ? (alpha + endv) : -1e30f;
    float mz = v;
    for (int o = 16; o > 0; o >>= 1) mz = fmaxf(mz, __shfl_xor(mz, o, 32));
    float ez = act ? __expf(v - mz) : 0.0f;
    for (int o = 16; o > 0; o >>= 1) ez += __shfl_xor(ez, o, 32);
    float logZ = mz + __logf(ez);
    if (j == 0) atomicAdd(out, logZ - num);
}

__global__ void k_sentinel(float* out) {
    if (threadIdx.x == 0 && blockIdx.x == 0) out[0] = 123456.0f;
}

// ---------------------------------------------------------------------------
extern "C" void kernel_launch(void* const* d_in, const int* in_sizes, int n_in,
                              void* d_out, int out_size, void* d_ws, size_t ws_size,
                              hipStream_t stream) {
    const int*   x    = (const int*)d_in[0];
    const int*   y    = (const int*)d_in[1];
    const int*   sl   = (const int*)d_in[2];
    const float* emb  = (const float*)d_in[3];
    const float* wihf = (const float*)d_in[4];
    const float* whhf = (const float*)d_in[5];
    const float* bihf = (const float*)d_in[6];
    const float* bhhf = (const float*)d_in[7];
    const float* wihb = (const float*)d_in[8];
    const float* whhb = (const float*)d_in[9];
    const float* bihb = (const float*)d_in[10];
    const float* bhhb = (const float*)d_in[11];
    const float* wlin = (const float*)d_in[12];
    const float* blin = (const float*)d_in[13];
    const float* st   = (const float*)d_in[14];
    const float* en   = (const float*)d_in[15];
    const float* tr   = (const float*)d_in[16];

    const size_t OFF_XG   = 0;
    const size_t OFF_XSB  = 268435456;
    const size_t OFF_WCAT = 301989888;
    const size_t OFF_HF   = 306184192;
    const size_t OFF_HB   = 339738624;
    const size_t OFF_EM   = 373293056;
    const size_t OFF_WLP  = 376045568;
    const size_t OFF_CNT  = 376111104;
    const size_t NEEDED   = OFF_CNT + 8192;

    if (ws_size < NEEDED) {
        k_sentinel<<<1, 64, 0, stream>>>((float*)d_out);
        return;
    }
    char* ws = (char*)d_ws;
    u16*      xg   = (u16*)(ws + OFF_XG);
    u16*      xsb  = (u16*)(ws + OFF_XSB);
    u16*      wcat = (u16*)(ws + OFF_WCAT);
    u16*      hf   = (u16*)(ws + OFF_HF);
    u16*      hb   = (u16*)(ws + OFF_HB);
    float*    em   = (float*)(ws + OFF_EM);
    u16*      wlp  = (u16*)(ws + OFF_WLP);
    unsigned* ctl  = (unsigned*)(ws + OFF_CNT);

    hipMemsetAsync(ctl, 0, 8192, stream);
    hipMemsetAsync(d_out, 0, sizeof(float), stream);

    k_prep<<<9232, 256, 0, stream>>>(x, emb, wihf, wihb, wlin, xsb, wcat, wlp);
    k_gemm_xg<<<dim3(256, 32), 256, 0, stream>>>(xsb, wcat, bihf, bhhf, bihb, bhhb, xg);
    k_lstm<<<128, 512, 0, stream>>>(xg, whhf, whhb, hf, hb, ctl);
    k_em<<<256, 256, 0, stream>>>(hf, hb, wlp, blin, em);
    k_crf<<<64, 64, 0, stream>>>(em, y, sl, st, en, tr, (float*)d_out);
}